// Round 6
// baseline (1062.251 us; speedup 1.0000x reference)
//
#include <hip/hip_runtime.h>
#include <hip/hip_bf16.h>
#include <stdint.h>
#include <stddef.h>

// MoE: T=4096 tokens, D=1024, H=4096, E=8, top-2. fp32 in/out, bf16 MFMA inside.
// Round 6: r5 pipeline unchanged + 4 ablation probe dispatches (VAR template):
//   VAR 0 = full (real pipeline)          VAR 1 = no-MFMA (frag sink)
//   VAR 2 = no-ds_read (zero frags)       VAR 3 = no-stage (no gload_lds)
//   VAR 5 = stage from fixed k-tile (L2-hot source)
// Probes write to hbuf (dead after GEMM2) — output unaffected, per-dispatch
// durations in rocprof separate the candidate walls.

#define T_TOK 4096
#define DIM   1024
#define HID   4096
#define NE    8
#define MT_MAX 40

typedef unsigned short u16;
typedef __bf16 bf16x8 __attribute__((ext_vector_type(8)));
typedef float  f32x4  __attribute__((ext_vector_type(4)));
typedef u16    u16x8  __attribute__((ext_vector_type(8)));

__device__ __forceinline__ u16 f2bf(float f) {
  union { float f; uint32_t u; } v; v.f = f;
  uint32_t u = v.u;
  return (u16)((u + 0x7fffu + ((u >> 16) & 1u)) >> 16);   // RNE
}

__device__ __forceinline__ void async_load16(const void* g, void* l) {
  typedef __attribute__((address_space(1))) void GPtr;
  typedef __attribute__((address_space(3))) void LPtr;
  __builtin_amdgcn_global_load_lds((GPtr*)g, (LPtr*)l, 16, 0, 0);
}

// ---------------- Router ----------------------------------------------------
__global__ void router_kernel(const float* __restrict__ x, const float* __restrict__ Wr,
                              const float* __restrict__ br, const float* __restrict__ gb,
                              int* __restrict__ counts, int* __restrict__ lists,
                              float* __restrict__ gate_p) {
  const int t = blockIdx.x * 4 + (threadIdx.x >> 6);
  const int lane = threadIdx.x & 63;
  const float* xr = x + (size_t)t * DIM;
  float acc[NE];
#pragma unroll
  for (int e = 0; e < NE; ++e) acc[e] = 0.f;
#pragma unroll
  for (int i = 0; i < DIM / 64; ++i) {
    const int k = i * 64 + lane;
    const float xv = xr[k];
    const float4 w0 = *reinterpret_cast<const float4*>(Wr + (size_t)k * NE);
    const float4 w1 = *reinterpret_cast<const float4*>(Wr + (size_t)k * NE + 4);
    acc[0] += xv * w0.x; acc[1] += xv * w0.y; acc[2] += xv * w0.z; acc[3] += xv * w0.w;
    acc[4] += xv * w1.x; acc[5] += xv * w1.y; acc[6] += xv * w1.z; acc[7] += xv * w1.w;
  }
#pragma unroll
  for (int off = 32; off >= 1; off >>= 1) {
#pragma unroll
    for (int e = 0; e < NE; ++e) acc[e] += __shfl_xor(acc[e], off);
  }
  if (lane == 0) {
    float lg[NE];
#pragma unroll
    for (int e = 0; e < NE; ++e) lg[e] = acc[e] + br[e] + gb[e];
    int i0 = 0;
#pragma unroll
    for (int e = 1; e < NE; ++e) if (lg[e] > lg[i0]) i0 = e;
    int i1 = (i0 == 0) ? 1 : 0;
#pragma unroll
    for (int e = 0; e < NE; ++e) if (e != i0 && lg[e] > lg[i1]) i1 = e;
    const float ev = expf(lg[i1] - lg[i0]);
    const float p0 = 1.f / (1.f + ev);
    const float p1 = ev / (1.f + ev);
    const int pos0 = atomicAdd(&counts[i0], 1);
    lists[i0 * T_TOK + pos0] = t * 2 + 0;
    const int pos1 = atomicAdd(&counts[i1], 1);
    lists[i1 * T_TOK + pos1] = t * 2 + 1;
    gate_p[t * 2 + 0] = p0;
    gate_p[t * 2 + 1] = p1;
  }
}

// ---------------- tile table ------------------------------------------------
__global__ void tile_table_kernel(const int* __restrict__ counts, int* __restrict__ tab) {
  if (threadIdx.x == 0) {
    int tot = 0;
    for (int e = 0; e < NE; ++e) {
      const int c = counts[e];
      const int nt = (c + 255) >> 8;
      for (int i = 0; i < nt && tot < MT_MAX; ++i) {
        tab[tot * 2] = e; tab[tot * 2 + 1] = i * 256; ++tot;
      }
    }
    for (; tot < MT_MAX; ++tot) tab[tot * 2] = -1;
  }
}

// ---------------- fp32 -> bf16 (x) ------------------------------------------
__global__ void cvt_x_kernel(const float* __restrict__ in, u16* __restrict__ out, int n8) {
  const int i = blockIdx.x * blockDim.x + threadIdx.x;
  if (i >= n8) return;
  const float4 a = reinterpret_cast<const float4*>(in)[2 * i];
  const float4 b = reinterpret_cast<const float4*>(in)[2 * i + 1];
  u16x8 r;
  r[0] = f2bf(a.x); r[1] = f2bf(a.y); r[2] = f2bf(a.z); r[3] = f2bf(a.w);
  r[4] = f2bf(b.x); r[5] = f2bf(b.y); r[6] = f2bf(b.z); r[7] = f2bf(b.w);
  *reinterpret_cast<u16x8*>(out + (size_t)i * 8) = r;
}

// ---------------- fp32 [E][K][N] -> bf16 [E][N][K] --------------------------
__global__ void cvt_w_kernel(const float* __restrict__ in, u16* __restrict__ out,
                             int K, int N) {
  __shared__ float tile[64][65];
  const int e = blockIdx.z;
  const int n0 = blockIdx.x * 64, k0 = blockIdx.y * 64;
  const int tid = threadIdx.x;
  const float* src = in + (size_t)e * K * N;
#pragma unroll
  for (int r = 0; r < 16; ++r) {
    const int kr = r * 4 + (tid >> 6);
    tile[kr][tid & 63] = src[(size_t)(k0 + kr) * N + n0 + (tid & 63)];
  }
  __syncthreads();
  u16* dst = out + (size_t)e * N * K;
#pragma unroll
  for (int r = 0; r < 8; ++r) {
    const int nr = r * 8 + (tid >> 5);
    const int kc = (tid & 31) * 2;
    ushort2 v;
    v.x = f2bf(tile[kc][nr]);
    v.y = f2bf(tile[kc + 1][nr]);
    *reinterpret_cast<ushort2*>(&dst[(size_t)(n0 + nr) * K + k0 + kc]) = v;
  }
}

// ---------------- Grouped GEMM: 8-phase counted-vmcnt pipeline ---------------
template <int KT, int NT, int NSPLIT, int PHASE, int VAR = 0>
__global__ __launch_bounds__(512, 2)
void gemm_kernel(const u16* __restrict__ Abase, const u16* __restrict__ Bt,
                 const float* __restrict__ bias, const int* __restrict__ counts,
                 const int* __restrict__ lists, const float* __restrict__ gate_p,
                 const int* __restrict__ tab,
                 u16* __restrict__ hout, float* __restrict__ yout) {
  const int e = tab[blockIdx.x * 2];
  if (e < 0) return;
  const int m0 = tab[blockIdx.x * 2 + 1];
  const int cnt = counts[e];
  const int n0 = blockIdx.y * 256;
  const int z = blockIdx.z;
  const int kbase = z * (KT / NSPLIT);
  constexpr int nkt = (KT / NSPLIT) / 64;
  constexpr int niter = nkt / 2;

  const int tid = threadIdx.x;
  const int lane = tid & 63, w = tid >> 6;
  const int wm = w >> 2, wn = w & 3;
  const int bh = wn >> 1, bs = wn & 1;
  const int l15 = lane & 15, lks = lane >> 4;

  __shared__ alignas(16) u16 lds[65536];      // 128 KB
  __shared__ int rowp[256];

  if (tid < 256) {
    const int idx = m0 + tid;
    rowp[tid] = lists[e * T_TOK + (idx < cnt ? idx : cnt - 1)];
  }
  __syncthreads();

  const int sslot = (tid & 7) ^ ((tid >> 3) & 7);
  const u16* aPtr[2][2];
  const u16* bPtr[2][2];
#pragma unroll
  for (int h = 0; h < 2; ++h)
#pragma unroll
    for (int s = 0; s < 2; ++s) {
      const int r = h * 128 + s * 64 + (tid >> 3);
      const int p = rowp[r];
      const int arow = (PHASE == 1) ? (p >> 1) : p;
      aPtr[h][s] = Abase + (size_t)arow * KT + kbase + sslot * 8;
      bPtr[h][s] = Bt + ((size_t)e * NT + n0 + r) * KT + kbase + sslot * 8;
    }

  int aoff[2];
#pragma unroll
  for (int k = 0; k < 2; ++k)
    aoff[k] = l15 * 64 + (((k * 4 + lks) ^ (l15 & 7)) * 8);

  f32x4 acc[8][4];
#pragma unroll
  for (int a = 0; a < 8; ++a)
#pragma unroll
    for (int b = 0; b < 4; ++b) acc[a][b] = f32x4{0.f, 0.f, 0.f, 0.f};

  bf16x8 af[4][2] = {};
  bf16x8 bfr[4][2] = {};

#define RDA(C, FMH)                                                            \
  if constexpr (VAR != 2) {                                                    \
    _Pragma("unroll") for (int f_ = 0; f_ < 4; ++f_)                           \
    _Pragma("unroll") for (int k_ = 0; k_ < 2; ++k_)                           \
      af[f_][k_] = *reinterpret_cast<const bf16x8*>(                           \
          &lds[(((C) * 2 + wm) * 2 + (FMH)) * 4096 + f_ * 1024 + aoff[k_]]);   \
  }

#define RDB(C)                                                                 \
  if constexpr (VAR != 2) {                                                    \
    _Pragma("unroll") for (int g_ = 0; g_ < 4; ++g_)                           \
    _Pragma("unroll") for (int k_ = 0; k_ < 2; ++k_)                           \
      bfr[g_][k_] = *reinterpret_cast<const bf16x8*>(                          \
          &lds[32768 + (((C) * 2 + bh) * 2 + bs) * 4096 + g_ * 1024 + aoff[k_]]); \
  }

#define SGA(C, S, TT)                                                          \
  if constexpr (VAR != 3) {                                                    \
    const int tsrc_ = (VAR == 5) ? 0 : (TT);                                   \
    _Pragma("unroll") for (int h_ = 0; h_ < 2; ++h_)                           \
      async_load16(aPtr[h_][S] + tsrc_ * 64,                                   \
                   &lds[(((C) * 2 + h_) * 2 + (S)) * 4096 + w * 512]);         \
  }

#define SGB(C, H, TT)                                                          \
  if constexpr (VAR != 3) {                                                    \
    const int tsrc_ = (VAR == 5) ? 0 : (TT);                                   \
    _Pragma("unroll") for (int s_ = 0; s_ < 2; ++s_)                           \
      async_load16(bPtr[H][s_] + tsrc_ * 64,                                   \
                   &lds[32768 + (((C) * 2 + (H)) * 2 + s_) * 4096 + w * 512]); \
  }

#define MMQ(FMH, FNH)                                                          \
  _Pragma("unroll") for (int f_ = 0; f_ < 4; ++f_)                             \
  _Pragma("unroll") for (int g_ = 0; g_ < 2; ++g_)                             \
  _Pragma("unroll") for (int k_ = 0; k_ < 2; ++k_)                             \
    acc[(FMH) * 4 + f_][(FNH) * 2 + g_] =                                      \
        __builtin_amdgcn_mfma_f32_16x16x32_bf16(                               \
            af[f_][k_], bfr[(FNH) * 2 + g_][k_],                               \
            acc[(FMH) * 4 + f_][(FNH) * 2 + g_], 0, 0, 0);

#define SINKALL()                                                              \
  _Pragma("unroll") for (int f_ = 0; f_ < 4; ++f_) {                           \
    asm volatile("" :: "v"(af[f_][0]), "v"(af[f_][1]),                         \
                       "v"(bfr[f_][0]), "v"(bfr[f_][1]));                      \
  }

#define CORE(FMH, FNH)                                                         \
  __builtin_amdgcn_s_barrier();                                                \
  asm volatile("s_waitcnt lgkmcnt(0)" ::: "memory");                           \
  __builtin_amdgcn_sched_barrier(0);                                           \
  if constexpr (VAR != 1) {                                                    \
    __builtin_amdgcn_s_setprio(1);                                             \
    MMQ(FMH, FNH);                                                             \
    __builtin_amdgcn_s_setprio(0);                                             \
  } else { SINKALL(); }                                                        \
  __builtin_amdgcn_sched_barrier(0);

#define BAR() __builtin_amdgcn_s_barrier();

#define ITER(T, LAST)                                                          \
  {                                                                            \
    RDA(0, 0); RDB(0);                                                         \
    SGA(1, 1, (T) + 1);                                                        \
    CORE(0, 0) BAR()                                                           \
    if (!(LAST)) { SGA(0, 0, (T) + 2); }                                       \
    CORE(0, 1) BAR()                                                           \
    RDA(0, 1);                                                                 \
    if (!(LAST)) { SGB(0, 0, (T) + 2); }                                       \
    CORE(1, 0) BAR()                                                           \
    if (!(LAST)) { SGB(0, 1, (T) + 2); }                                       \
    CORE(1, 1)                                                                 \
    if (LAST) { asm volatile("s_waitcnt vmcnt(0)" ::: "memory"); }             \
    else      { asm volatile("s_waitcnt vmcnt(6)" ::: "memory"); }             \
    __builtin_amdgcn_sched_barrier(0);                                         \
    BAR()                                                                      \
    RDA(1, 0); RDB(1);                                                         \
    if (!(LAST)) { SGA(0, 1, (T) + 2); }                                       \
    CORE(0, 0) BAR()                                                           \
    if (!(LAST)) { SGA(1, 0, (T) + 3); }                                       \
    CORE(0, 1) BAR()                                                           \
    RDA(1, 1);                                                                 \
    if (!(LAST)) { SGB(1, 0, (T) + 3); }                                       \
    CORE(1, 0) BAR()                                                           \
    if (!(LAST)) { SGB(1, 1, (T) + 3); }                                       \
    CORE(1, 1)                                                                 \
    if (!(LAST)) {                                                             \
      asm volatile("s_waitcnt vmcnt(6)" ::: "memory");                         \
      __builtin_amdgcn_sched_barrier(0);                                       \
    }                                                                          \
    BAR()                                                                      \
  }

  // ---- prologue ----
  SGA(0, 0, 0); SGB(0, 0, 0); SGB(0, 1, 0); SGA(0, 1, 0);
  SGA(1, 0, 1); SGB(1, 0, 1); SGB(1, 1, 1);
  asm volatile("s_waitcnt vmcnt(6)" ::: "memory");
  __builtin_amdgcn_sched_barrier(0);
  __builtin_amdgcn_s_barrier();

  for (int it = 0; it < niter - 1; ++it) {
    const int t = 2 * it;
    ITER(t, false);
  }
  ITER(nkt - 2, true);

#undef ITER
#undef CORE
#undef SINKALL
#undef MMQ
#undef SGB
#undef SGA
#undef RDB
#undef RDA
#undef BAR

  // ---- epilogue ----
  const float* bias_e = bias + (size_t)e * NT;
  const float bz = (z == 0) ? 1.f : 0.f;
#pragma unroll
  for (int fm = 0; fm < 8; ++fm) {
    const int rbase = wm * 128 + (fm >> 2) * 64 + (fm & 3) * 16 + (lane >> 4) * 4;
#pragma unroll
    for (int r = 0; r < 4; ++r) {
      const int row = rbase + r;
      if (m0 + row >= cnt) continue;
      const int p = rowp[row];
#pragma unroll
      for (int nf = 0; nf < 4; ++nf) {
        const int n = n0 + wn * 64 + nf * 16 + l15;
        const float v = acc[fm][nf][r];
        if (PHASE == 1) {
          const float vb = v + bias_e[n];
          const float g = 0.5f * vb * (1.0f + erff(vb * 0.70710678118654752f));
          hout[(size_t)p * NT + n] = f2bf(g);
        } else if (PHASE == 2) {
          yout[(size_t)z * T_TOK * 2 * NT + (size_t)p * NT + n] =
              gate_p[p] * (v + bz * bias_e[n]);
        } else {
          atomicAdd(&yout[(size_t)(p >> 1) * NT + n], gate_p[p] * (v + bz * bias_e[n]));
        }
      }
    }
  }
}

// ---------------- combine ----------------------------------------------------
__global__ void combine4_kernel(const float* __restrict__ yp, float* __restrict__ out) {
  const int i = blockIdx.x * blockDim.x + threadIdx.x;
  const int t = i >> 8, d4 = i & 255;
  const size_t r0 = (size_t)(2 * t) * 256 + d4;
  const size_t zoff = (size_t)T_TOK * 2 * DIM / 4;
  const float4 a = reinterpret_cast<const float4*>(yp)[r0];
  const float4 b = reinterpret_cast<const float4*>(yp)[r0 + 256];
  const float4 c = reinterpret_cast<const float4*>(yp)[zoff + r0];
  const float4 d = reinterpret_cast<const float4*>(yp)[zoff + r0 + 256];
  float4 o;
  o.x = a.x + b.x + c.x + d.x; o.y = a.y + b.y + c.y + d.y;
  o.z = a.z + b.z + c.z + d.z; o.w = a.w + b.w + c.w + d.w;
  reinterpret_cast<float4*>(out)[i] = o;
}

extern "C" void kernel_launch(void* const* d_in, const int* in_sizes, int n_in,
                              void* d_out, int out_size, void* d_ws, size_t ws_size,
                              hipStream_t stream) {
  const float* x  = (const float*)d_in[0];
  const float* Wr = (const float*)d_in[1];
  const float* br = (const float*)d_in[2];
  const float* gb = (const float*)d_in[3];
  const float* W1 = (const float*)d_in[4];
  const float* b1 = (const float*)d_in[5];
  const float* W2 = (const float*)d_in[6];
  const float* b2 = (const float*)d_in[7];
  float* out = (float*)d_out;

  char* ws = (char*)d_ws;
  size_t off = 0;
  int*   counts = (int*)(ws + off);   off += 256;
  int*   ttab   = (int*)(ws + off);   off += 512;
  int*   lists  = (int*)(ws + off);   off += (size_t)NE * T_TOK * 4;
  float* gate_p = (float*)(ws + off); off += (size_t)T_TOK * 2 * 4;
  u16*   xb     = (u16*)(ws + off);   off += (size_t)T_TOK * DIM * 2;
  u16*   wbuf   = (u16*)(ws + off);   off += (size_t)NE * DIM * HID * 2;
  u16*   hbuf   = (u16*)(ws + off);   off += (size_t)T_TOK * 2 * HID * 2;
  float* ypair  = (float*)(ws + off);
  const size_t need_full = off + (size_t)2 * T_TOK * 2 * DIM * 4;
  const bool use_ypair = (ws_size >= need_full);

  hipMemsetAsync(counts, 0, 32, stream);
  router_kernel<<<T_TOK / 4, 256, 0, stream>>>(x, Wr, br, gb, counts, lists, gate_p);
  tile_table_kernel<<<1, 64, 0, stream>>>(counts, ttab);
  cvt_x_kernel<<<(T_TOK * DIM / 8 + 255) / 256, 256, 0, stream>>>(x, xb, T_TOK * DIM / 8);
  cvt_w_kernel<<<dim3(HID / 64, DIM / 64, NE), 256, 0, stream>>>(W1, wbuf, DIM, HID);
  gemm_kernel<DIM, HID, 1, 1><<<dim3(MT_MAX, HID / 256, 1), 512, 0, stream>>>(
      xb, wbuf, b1, counts, lists, gate_p, ttab, hbuf, nullptr);
  cvt_w_kernel<<<dim3(DIM / 64, HID / 64, NE), 256, 0, stream>>>(W2, wbuf, HID, DIM);
  if (use_ypair) {
    gemm_kernel<HID, DIM, 2, 2><<<dim3(MT_MAX, DIM / 256, 2), 512, 0, stream>>>(
        hbuf, wbuf, b2, counts, lists, gate_p, ttab, nullptr, ypair);
    combine4_kernel<<<T_TOK * DIM / 4 / 256, 256, 0, stream>>>(ypair, out);
  } else {
    hipMemsetAsync(out, 0, (size_t)out_size * 4, stream);
    gemm_kernel<HID, DIM, 2, 3><<<dim3(MT_MAX, DIM / 256, 2), 512, 0, stream>>>(
        hbuf, wbuf, b2, counts, lists, gate_p, ttab, nullptr, out);
  }

  // ---- ablation probes (after real pipeline; sink = hbuf, now dead).
  // Dispatch order (ascending Dispatch_Id among last 4 gemm dispatches):
  //   V1 no-MFMA, V2 no-dsread, V3 no-stage, V5 L2-hot-stage.
  gemm_kernel<DIM, HID, 1, 1, 1><<<dim3(MT_MAX, HID / 256, 1), 512, 0, stream>>>(
      xb, wbuf, b1, counts, lists, gate_p, ttab, hbuf, nullptr);
  gemm_kernel<DIM, HID, 1, 1, 2><<<dim3(MT_MAX, HID / 256, 1), 512, 0, stream>>>(
      xb, wbuf, b1, counts, lists, gate_p, ttab, hbuf, nullptr);
  gemm_kernel<DIM, HID, 1, 1, 3><<<dim3(MT_MAX, HID / 256, 1), 512, 0, stream>>>(
      xb, wbuf, b1, counts, lists, gate_p, ttab, hbuf, nullptr);
  gemm_kernel<DIM, HID, 1, 1, 5><<<dim3(MT_MAX, HID / 256, 1), 512, 0, stream>>>(
      xb, wbuf, b1, counts, lists, gate_p, ttab, hbuf, nullptr);
}

// Round 7
// 508.026 us; speedup vs baseline: 2.0909x; 2.0909x over previous
//
#include <hip/hip_runtime.h>
#include <hip/hip_bf16.h>
#include <stdint.h>
#include <stddef.h>

// MoE: T=4096 tokens, D=1024, H=4096, E=8, top-2. fp32 in/out, bf16 MFMA inside.
// Round 7: channel-camping fix. All GEMM streams repacked at 128B-row k-tile
// granularity so no stream strides by a multiple of 2KB:
//   xbP  [D/64][T][64]      (cvt_x writes packed)
//   W1tP [E][D/64][H][64], W2tP [E][H/64][D][64]  (cvt_w writes packed)
//   hbufP[H/64][2T][64]     (GEMM1 epilogue writes packed; GEMM2 A reads it)
// GEMM schedule identical to r5 (8-phase counted vmcnt(6), XOR swizzle, setprio).

#define T_TOK 4096
#define DIM   1024
#define HID   4096
#define NE    8
#define MT_MAX 40

typedef unsigned short u16;
typedef __bf16 bf16x8 __attribute__((ext_vector_type(8)));
typedef float  f32x4  __attribute__((ext_vector_type(4)));
typedef u16    u16x8  __attribute__((ext_vector_type(8)));

__device__ __forceinline__ u16 f2bf(float f) {
  union { float f; uint32_t u; } v; v.f = f;
  uint32_t u = v.u;
  return (u16)((u + 0x7fffu + ((u >> 16) & 1u)) >> 16);   // RNE
}

__device__ __forceinline__ void async_load16(const void* g, void* l) {
  typedef __attribute__((address_space(1))) void GPtr;
  typedef __attribute__((address_space(3))) void LPtr;
  __builtin_amdgcn_global_load_lds((GPtr*)g, (LPtr*)l, 16, 0, 0);
}

// ---------------- Router ----------------------------------------------------
__global__ void router_kernel(const float* __restrict__ x, const float* __restrict__ Wr,
                              const float* __restrict__ br, const float* __restrict__ gb,
                              int* __restrict__ counts, int* __restrict__ lists,
                              float* __restrict__ gate_p) {
  const int t = blockIdx.x * 4 + (threadIdx.x >> 6);
  const int lane = threadIdx.x & 63;
  const float* xr = x + (size_t)t * DIM;
  float acc[NE];
#pragma unroll
  for (int e = 0; e < NE; ++e) acc[e] = 0.f;
#pragma unroll
  for (int i = 0; i < DIM / 64; ++i) {
    const int k = i * 64 + lane;
    const float xv = xr[k];
    const float4 w0 = *reinterpret_cast<const float4*>(Wr + (size_t)k * NE);
    const float4 w1 = *reinterpret_cast<const float4*>(Wr + (size_t)k * NE + 4);
    acc[0] += xv * w0.x; acc[1] += xv * w0.y; acc[2] += xv * w0.z; acc[3] += xv * w0.w;
    acc[4] += xv * w1.x; acc[5] += xv * w1.y; acc[6] += xv * w1.z; acc[7] += xv * w1.w;
  }
#pragma unroll
  for (int off = 32; off >= 1; off >>= 1) {
#pragma unroll
    for (int e = 0; e < NE; ++e) acc[e] += __shfl_xor(acc[e], off);
  }
  if (lane == 0) {
    float lg[NE];
#pragma unroll
    for (int e = 0; e < NE; ++e) lg[e] = acc[e] + br[e] + gb[e];
    int i0 = 0;
#pragma unroll
    for (int e = 1; e < NE; ++e) if (lg[e] > lg[i0]) i0 = e;
    int i1 = (i0 == 0) ? 1 : 0;
#pragma unroll
    for (int e = 0; e < NE; ++e) if (e != i0 && lg[e] > lg[i1]) i1 = e;
    const float ev = expf(lg[i1] - lg[i0]);
    const float p0 = 1.f / (1.f + ev);
    const float p1 = ev / (1.f + ev);
    const int pos0 = atomicAdd(&counts[i0], 1);
    lists[i0 * T_TOK + pos0] = t * 2 + 0;
    const int pos1 = atomicAdd(&counts[i1], 1);
    lists[i1 * T_TOK + pos1] = t * 2 + 1;
    gate_p[t * 2 + 0] = p0;
    gate_p[t * 2 + 1] = p1;
  }
}

// ---------------- tile table ------------------------------------------------
__global__ void tile_table_kernel(const int* __restrict__ counts, int* __restrict__ tab) {
  if (threadIdx.x == 0) {
    int tot = 0;
    for (int e = 0; e < NE; ++e) {
      const int c = counts[e];
      const int nt = (c + 255) >> 8;
      for (int i = 0; i < nt && tot < MT_MAX; ++i) {
        tab[tot * 2] = e; tab[tot * 2 + 1] = i * 256; ++tot;
      }
    }
    for (; tot < MT_MAX; ++tot) tab[tot * 2] = -1;
  }
}

// ---------------- fp32 [T][D] -> bf16 packed [D/64][T][64] -------------------
__global__ void cvt_x_kernel(const float* __restrict__ in, u16* __restrict__ out) {
  const int i = blockIdx.x * blockDim.x + threadIdx.x;   // over T*D/8
  const int t = i >> 7;          // D/8 = 128 chunks per row
  const int d0 = (i & 127) * 8;
  const float4 a = *reinterpret_cast<const float4*>(in + (size_t)t * DIM + d0);
  const float4 b = *reinterpret_cast<const float4*>(in + (size_t)t * DIM + d0 + 4);
  u16x8 r;
  r[0] = f2bf(a.x); r[1] = f2bf(a.y); r[2] = f2bf(a.z); r[3] = f2bf(a.w);
  r[4] = f2bf(b.x); r[5] = f2bf(b.y); r[6] = f2bf(b.z); r[7] = f2bf(b.w);
  *reinterpret_cast<u16x8*>(out + (size_t)(d0 >> 6) * (T_TOK * 64) +
                            (size_t)t * 64 + (d0 & 63)) = r;
}

// ------- fp32 [E][K][N] -> bf16 packed [E][K/64][N][64] ----------------------
__global__ void cvt_w_kernel(const float* __restrict__ in, u16* __restrict__ out,
                             int K, int N) {
  __shared__ float tile[64][65];
  const int e = blockIdx.z;
  const int n0 = blockIdx.x * 64, k0 = blockIdx.y * 64;
  const int tid = threadIdx.x;
  const float* src = in + (size_t)e * K * N;
#pragma unroll
  for (int r = 0; r < 16; ++r) {
    const int kr = r * 4 + (tid >> 6);
    tile[kr][tid & 63] = src[(size_t)(k0 + kr) * N + n0 + (tid & 63)];
  }
  __syncthreads();
  u16* dst = out + (size_t)e * K * N + (size_t)(k0 >> 6) * ((size_t)N * 64);
#pragma unroll
  for (int r = 0; r < 8; ++r) {
    const int nr = r * 8 + (tid >> 5);
    const int kc = (tid & 31) * 2;
    ushort2 v;
    v.x = f2bf(tile[kc][nr]);
    v.y = f2bf(tile[kc + 1][nr]);
    *reinterpret_cast<ushort2*>(&dst[(size_t)(n0 + nr) * 64 + kc]) = v;
  }
}

// ---------------- Grouped GEMM: 8-phase counted-vmcnt pipeline ---------------
// A packed: row r's k-tile kt chunk at  Abase + kt*AKT + r*64   (AKT = rows*64)
// B packed: row n's k-tile kt chunk at  Bt + e*NT*KT + kt*BKT + n*64
template <int KT, int NT, int NSPLIT, int PHASE>
__global__ __launch_bounds__(512, 2)
void gemm_kernel(const u16* __restrict__ Abase, const u16* __restrict__ Bt,
                 const float* __restrict__ bias, const int* __restrict__ counts,
                 const int* __restrict__ lists, const float* __restrict__ gate_p,
                 const int* __restrict__ tab,
                 u16* __restrict__ hout, float* __restrict__ yout) {
  const int e = tab[blockIdx.x * 2];
  if (e < 0) return;
  const int m0 = tab[blockIdx.x * 2 + 1];
  const int cnt = counts[e];
  const int n0 = blockIdx.y * 256;
  const int z = blockIdx.z;
  const int kb64 = z * ((KT / NSPLIT) / 64);
  constexpr int nkt = (KT / NSPLIT) / 64;
  constexpr int niter = nkt / 2;
  constexpr size_t AKT = (PHASE == 1) ? (size_t)T_TOK * 64 : (size_t)T_TOK * 2 * 64;
  constexpr size_t BKT = (size_t)NT * 64;
  constexpr size_t HSLAB = (size_t)T_TOK * 2 * 64;

  const int tid = threadIdx.x;
  const int lane = tid & 63, w = tid >> 6;
  const int wm = w >> 2, wn = w & 3;
  const int bh = wn >> 1, bs = wn & 1;
  const int l15 = lane & 15, lks = lane >> 4;

  __shared__ alignas(16) u16 lds[65536];      // 128 KB
  __shared__ int rowp[256];

  if (tid < 256) {
    const int idx = m0 + tid;
    rowp[tid] = lists[e * T_TOK + (idx < cnt ? idx : cnt - 1)];
  }
  __syncthreads();

  const int sslot = (tid & 7) ^ ((tid >> 3) & 7);
  const u16* aPtr[2][2];
  const u16* bPtr[2][2];
#pragma unroll
  for (int h = 0; h < 2; ++h)
#pragma unroll
    for (int s = 0; s < 2; ++s) {
      const int r = h * 128 + s * 64 + (tid >> 3);
      const int p = rowp[r];
      const int arow = (PHASE == 1) ? (p >> 1) : p;
      aPtr[h][s] = Abase + (size_t)kb64 * AKT + (size_t)arow * 64 + sslot * 8;
      bPtr[h][s] = Bt + (size_t)e * NT * KT + (size_t)kb64 * BKT +
                   (size_t)(n0 + r) * 64 + sslot * 8;
    }

  int aoff[2];
#pragma unroll
  for (int k = 0; k < 2; ++k)
    aoff[k] = l15 * 64 + (((k * 4 + lks) ^ (l15 & 7)) * 8);

  f32x4 acc[8][4];
#pragma unroll
  for (int a = 0; a < 8; ++a)
#pragma unroll
    for (int b = 0; b < 4; ++b) acc[a][b] = f32x4{0.f, 0.f, 0.f, 0.f};

  bf16x8 af[4][2], bfr[4][2];

#define RDA(C, FMH)                                                            \
  _Pragma("unroll") for (int f_ = 0; f_ < 4; ++f_)                             \
  _Pragma("unroll") for (int k_ = 0; k_ < 2; ++k_)                             \
    af[f_][k_] = *reinterpret_cast<const bf16x8*>(                             \
        &lds[(((C) * 2 + wm) * 2 + (FMH)) * 4096 + f_ * 1024 + aoff[k_]]);

#define RDB(C)                                                                 \
  _Pragma("unroll") for (int g_ = 0; g_ < 4; ++g_)                             \
  _Pragma("unroll") for (int k_ = 0; k_ < 2; ++k_)                             \
    bfr[g_][k_] = *reinterpret_cast<const bf16x8*>(                            \
        &lds[32768 + (((C) * 2 + bh) * 2 + bs) * 4096 + g_ * 1024 + aoff[k_]]);

#define SGA(C, S, TT)                                                          \
  _Pragma("unroll") for (int h_ = 0; h_ < 2; ++h_)                             \
    async_load16(aPtr[h_][S] + (size_t)(TT) * AKT,                             \
                 &lds[(((C) * 2 + h_) * 2 + (S)) * 4096 + w * 512]);

#define SGB(C, H, TT)                                                          \
  _Pragma("unroll") for (int s_ = 0; s_ < 2; ++s_)                             \
    async_load16(bPtr[H][s_] + (size_t)(TT) * BKT,                             \
                 &lds[32768 + (((C) * 2 + (H)) * 2 + s_) * 4096 + w * 512]);

#define MMQ(FMH, FNH)                                                          \
  _Pragma("unroll") for (int f_ = 0; f_ < 4; ++f_)                             \
  _Pragma("unroll") for (int g_ = 0; g_ < 2; ++g_)                             \
  _Pragma("unroll") for (int k_ = 0; k_ < 2; ++k_)                             \
    acc[(FMH) * 4 + f_][(FNH) * 2 + g_] =                                      \
        __builtin_amdgcn_mfma_f32_16x16x32_bf16(                               \
            af[f_][k_], bfr[(FNH) * 2 + g_][k_],                               \
            acc[(FMH) * 4 + f_][(FNH) * 2 + g_], 0, 0, 0);

#define CORE(FMH, FNH)                                                         \
  __builtin_amdgcn_s_barrier();                                                \
  asm volatile("s_waitcnt lgkmcnt(0)" ::: "memory");                           \
  __builtin_amdgcn_sched_barrier(0);                                           \
  __builtin_amdgcn_s_setprio(1);                                               \
  MMQ(FMH, FNH);                                                               \
  __builtin_amdgcn_s_setprio(0);                                               \
  __builtin_amdgcn_sched_barrier(0);

#define BAR() __builtin_amdgcn_s_barrier();

#define ITER(T, LAST)                                                          \
  {                                                                            \
    RDA(0, 0); RDB(0);                                                         \
    SGA(1, 1, (T) + 1);                                                        \
    CORE(0, 0) BAR()                                                           \
    if (!(LAST)) { SGA(0, 0, (T) + 2); }                                       \
    CORE(0, 1) BAR()                                                           \
    RDA(0, 1);                                                                 \
    if (!(LAST)) { SGB(0, 0, (T) + 2); }                                       \
    CORE(1, 0) BAR()                                                           \
    if (!(LAST)) { SGB(0, 1, (T) + 2); }                                       \
    CORE(1, 1)                                                                 \
    if (LAST) { asm volatile("s_waitcnt vmcnt(0)" ::: "memory"); }             \
    else      { asm volatile("s_waitcnt vmcnt(6)" ::: "memory"); }             \
    __builtin_amdgcn_sched_barrier(0);                                         \
    BAR()                                                                      \
    RDA(1, 0); RDB(1);                                                         \
    if (!(LAST)) { SGA(0, 1, (T) + 2); }                                       \
    CORE(0, 0) BAR()                                                           \
    if (!(LAST)) { SGA(1, 0, (T) + 3); }                                       \
    CORE(0, 1) BAR()                                                           \
    RDA(1, 1);                                                                 \
    if (!(LAST)) { SGB(1, 0, (T) + 3); }                                       \
    CORE(1, 0) BAR()                                                           \
    if (!(LAST)) { SGB(1, 1, (T) + 3); }                                       \
    CORE(1, 1)                                                                 \
    if (!(LAST)) {                                                             \
      asm volatile("s_waitcnt vmcnt(6)" ::: "memory");                         \
      __builtin_amdgcn_sched_barrier(0);                                       \
    }                                                                          \
    BAR()                                                                      \
  }

  // ---- prologue ----
  SGA(0, 0, 0); SGB(0, 0, 0); SGB(0, 1, 0); SGA(0, 1, 0);
  SGA(1, 0, 1); SGB(1, 0, 1); SGB(1, 1, 1);
  asm volatile("s_waitcnt vmcnt(6)" ::: "memory");
  __builtin_amdgcn_sched_barrier(0);
  __builtin_amdgcn_s_barrier();

  for (int it = 0; it < niter - 1; ++it) {
    const int t = 2 * it;
    ITER(t, false);
  }
  ITER(nkt - 2, true);

#undef ITER
#undef CORE
#undef MMQ
#undef SGB
#undef SGA
#undef RDB
#undef RDA
#undef BAR

  // ---- epilogue ----
  const float* bias_e = bias + (size_t)e * NT;
  const float bz = (z == 0) ? 1.f : 0.f;
#pragma unroll
  for (int fm = 0; fm < 8; ++fm) {
    const int rbase = wm * 128 + (fm >> 2) * 64 + (fm & 3) * 16 + (lane >> 4) * 4;
#pragma unroll
    for (int r = 0; r < 4; ++r) {
      const int row = rbase + r;
      if (m0 + row >= cnt) continue;
      const int p = rowp[row];
#pragma unroll
      for (int nf = 0; nf < 4; ++nf) {
        const int n = n0 + wn * 64 + nf * 16 + l15;
        const float v = acc[fm][nf][r];
        if (PHASE == 1) {
          const float vb = v + bias_e[n];
          const float g = 0.5f * vb * (1.0f + erff(vb * 0.70710678118654752f));
          hout[(size_t)(n >> 6) * HSLAB + (size_t)p * 64 + (n & 63)] = f2bf(g);
        } else if (PHASE == 2) {
          yout[(size_t)z * T_TOK * 2 * NT + (size_t)p * NT + n] =
              gate_p[p] * (v + bz * bias_e[n]);
        } else {
          atomicAdd(&yout[(size_t)(p >> 1) * NT + n], gate_p[p] * (v + bz * bias_e[n]));
        }
      }
    }
  }
}

// ---------------- combine ----------------------------------------------------
__global__ void combine4_kernel(const float* __restrict__ yp, float* __restrict__ out) {
  const int i = blockIdx.x * blockDim.x + threadIdx.x;
  const int t = i >> 8, d4 = i & 255;
  const size_t r0 = (size_t)(2 * t) * 256 + d4;
  const size_t zoff = (size_t)T_TOK * 2 * DIM / 4;
  const float4 a = reinterpret_cast<const float4*>(yp)[r0];
  const float4 b = reinterpret_cast<const float4*>(yp)[r0 + 256];
  const float4 c = reinterpret_cast<const float4*>(yp)[zoff + r0];
  const float4 d = reinterpret_cast<const float4*>(yp)[zoff + r0 + 256];
  float4 o;
  o.x = a.x + b.x + c.x + d.x; o.y = a.y + b.y + c.y + d.y;
  o.z = a.z + b.z + c.z + d.z; o.w = a.w + b.w + c.w + d.w;
  reinterpret_cast<float4*>(out)[i] = o;
}

extern "C" void kernel_launch(void* const* d_in, const int* in_sizes, int n_in,
                              void* d_out, int out_size, void* d_ws, size_t ws_size,
                              hipStream_t stream) {
  const float* x  = (const float*)d_in[0];
  const float* Wr = (const float*)d_in[1];
  const float* br = (const float*)d_in[2];
  const float* gb = (const float*)d_in[3];
  const float* W1 = (const float*)d_in[4];
  const float* b1 = (const float*)d_in[5];
  const float* W2 = (const float*)d_in[6];
  const float* b2 = (const float*)d_in[7];
  float* out = (float*)d_out;

  char* ws = (char*)d_ws;
  size_t off = 0;
  int*   counts = (int*)(ws + off);   off += 256;
  int*   ttab   = (int*)(ws + off);   off += 512;
  int*   lists  = (int*)(ws + off);   off += (size_t)NE * T_TOK * 4;
  float* gate_p = (float*)(ws + off); off += (size_t)T_TOK * 2 * 4;
  u16*   xb     = (u16*)(ws + off);   off += (size_t)T_TOK * DIM * 2;
  u16*   wbuf   = (u16*)(ws + off);   off += (size_t)NE * DIM * HID * 2;
  u16*   hbuf   = (u16*)(ws + off);   off += (size_t)T_TOK * 2 * HID * 2;
  float* ypair  = (float*)(ws + off);
  const size_t need_full = off + (size_t)2 * T_TOK * 2 * DIM * 4;
  const bool use_ypair = (ws_size >= need_full);

  hipMemsetAsync(counts, 0, 32, stream);
  router_kernel<<<T_TOK / 4, 256, 0, stream>>>(x, Wr, br, gb, counts, lists, gate_p);
  tile_table_kernel<<<1, 64, 0, stream>>>(counts, ttab);
  cvt_x_kernel<<<T_TOK * DIM / 8 / 256, 256, 0, stream>>>(x, xb);
  cvt_w_kernel<<<dim3(HID / 64, DIM / 64, NE), 256, 0, stream>>>(W1, wbuf, DIM, HID);
  gemm_kernel<DIM, HID, 1, 1><<<dim3(MT_MAX, HID / 256, 1), 512, 0, stream>>>(
      xb, wbuf, b1, counts, lists, gate_p, ttab, hbuf, nullptr);
  cvt_w_kernel<<<dim3(DIM / 64, HID / 64, NE), 256, 0, stream>>>(W2, wbuf, HID, DIM);
  if (use_ypair) {
    gemm_kernel<HID, DIM, 2, 2><<<dim3(MT_MAX, DIM / 256, 2), 512, 0, stream>>>(
        hbuf, wbuf, b2, counts, lists, gate_p, ttab, nullptr, ypair);
    combine4_kernel<<<T_TOK * DIM / 4 / 256, 256, 0, stream>>>(ypair, out);
  } else {
    hipMemsetAsync(out, 0, (size_t)out_size * 4, stream);
    gemm_kernel<HID, DIM, 2, 3><<<dim3(MT_MAX, DIM / 256, 2), 512, 0, stream>>>(
        hbuf, wbuf, b2, counts, lists, gate_p, ttab, nullptr, out);
  }
}

// Round 8
// 498.571 us; speedup vs baseline: 2.1306x; 1.0190x over previous
//
#include <hip/hip_runtime.h>
#include <hip/hip_bf16.h>
#include <stdint.h>
#include <stddef.h>

// MoE: T=4096 tokens, D=1024, H=4096, E=8, top-2. fp32 in/out, bf16 MFMA inside.
// Round 8: ONE variable vs r7 — minimum-sync 2-phase K-loop (3 sync events per
// k-tile: 2x lgkmcnt clusters + 1 vmcnt(0)+s_barrier), per the T3-minimum
// recipe (m248: 655-682 TF on grouped K=1024 @256^2). Layouts/epilogue/grid
// identical to r7 (packed 128B rows, tile table, XOR swizzle).

#define T_TOK 4096
#define DIM   1024
#define HID   4096
#define NE    8
#define MT_MAX 40

typedef unsigned short u16;
typedef __bf16 bf16x8 __attribute__((ext_vector_type(8)));
typedef float  f32x4  __attribute__((ext_vector_type(4)));
typedef u16    u16x8  __attribute__((ext_vector_type(8)));

__device__ __forceinline__ u16 f2bf(float f) {
  union { float f; uint32_t u; } v; v.f = f;
  uint32_t u = v.u;
  return (u16)((u + 0x7fffu + ((u >> 16) & 1u)) >> 16);   // RNE
}

__device__ __forceinline__ void async_load16(const void* g, void* l) {
  typedef __attribute__((address_space(1))) void GPtr;
  typedef __attribute__((address_space(3))) void LPtr;
  __builtin_amdgcn_global_load_lds((GPtr*)g, (LPtr*)l, 16, 0, 0);
}

// ---------------- Router ----------------------------------------------------
__global__ void router_kernel(const float* __restrict__ x, const float* __restrict__ Wr,
                              const float* __restrict__ br, const float* __restrict__ gb,
                              int* __restrict__ counts, int* __restrict__ lists,
                              float* __restrict__ gate_p) {
  const int t = blockIdx.x * 4 + (threadIdx.x >> 6);
  const int lane = threadIdx.x & 63;
  const float* xr = x + (size_t)t * DIM;
  float acc[NE];
#pragma unroll
  for (int e = 0; e < NE; ++e) acc[e] = 0.f;
#pragma unroll
  for (int i = 0; i < DIM / 64; ++i) {
    const int k = i * 64 + lane;
    const float xv = xr[k];
    const float4 w0 = *reinterpret_cast<const float4*>(Wr + (size_t)k * NE);
    const float4 w1 = *reinterpret_cast<const float4*>(Wr + (size_t)k * NE + 4);
    acc[0] += xv * w0.x; acc[1] += xv * w0.y; acc[2] += xv * w0.z; acc[3] += xv * w0.w;
    acc[4] += xv * w1.x; acc[5] += xv * w1.y; acc[6] += xv * w1.z; acc[7] += xv * w1.w;
  }
#pragma unroll
  for (int off = 32; off >= 1; off >>= 1) {
#pragma unroll
    for (int e = 0; e < NE; ++e) acc[e] += __shfl_xor(acc[e], off);
  }
  if (lane == 0) {
    float lg[NE];
#pragma unroll
    for (int e = 0; e < NE; ++e) lg[e] = acc[e] + br[e] + gb[e];
    int i0 = 0;
#pragma unroll
    for (int e = 1; e < NE; ++e) if (lg[e] > lg[i0]) i0 = e;
    int i1 = (i0 == 0) ? 1 : 0;
#pragma unroll
    for (int e = 0; e < NE; ++e) if (e != i0 && lg[e] > lg[i1]) i1 = e;
    const float ev = expf(lg[i1] - lg[i0]);
    const float p0 = 1.f / (1.f + ev);
    const float p1 = ev / (1.f + ev);
    const int pos0 = atomicAdd(&counts[i0], 1);
    lists[i0 * T_TOK + pos0] = t * 2 + 0;
    const int pos1 = atomicAdd(&counts[i1], 1);
    lists[i1 * T_TOK + pos1] = t * 2 + 1;
    gate_p[t * 2 + 0] = p0;
    gate_p[t * 2 + 1] = p1;
  }
}

// ---------------- tile table ------------------------------------------------
__global__ void tile_table_kernel(const int* __restrict__ counts, int* __restrict__ tab) {
  if (threadIdx.x == 0) {
    int tot = 0;
    for (int e = 0; e < NE; ++e) {
      const int c = counts[e];
      const int nt = (c + 255) >> 8;
      for (int i = 0; i < nt && tot < MT_MAX; ++i) {
        tab[tot * 2] = e; tab[tot * 2 + 1] = i * 256; ++tot;
      }
    }
    for (; tot < MT_MAX; ++tot) tab[tot * 2] = -1;
  }
}

// ---------------- fp32 [T][D] -> bf16 packed [D/64][T][64] -------------------
__global__ void cvt_x_kernel(const float* __restrict__ in, u16* __restrict__ out) {
  const int i = blockIdx.x * blockDim.x + threadIdx.x;   // over T*D/8
  const int t = i >> 7;
  const int d0 = (i & 127) * 8;
  const float4 a = *reinterpret_cast<const float4*>(in + (size_t)t * DIM + d0);
  const float4 b = *reinterpret_cast<const float4*>(in + (size_t)t * DIM + d0 + 4);
  u16x8 r;
  r[0] = f2bf(a.x); r[1] = f2bf(a.y); r[2] = f2bf(a.z); r[3] = f2bf(a.w);
  r[4] = f2bf(b.x); r[5] = f2bf(b.y); r[6] = f2bf(b.z); r[7] = f2bf(b.w);
  *reinterpret_cast<u16x8*>(out + (size_t)(d0 >> 6) * (T_TOK * 64) +
                            (size_t)t * 64 + (d0 & 63)) = r;
}

// ------- fp32 [E][K][N] -> bf16 packed [E][K/64][N][64] ----------------------
__global__ void cvt_w_kernel(const float* __restrict__ in, u16* __restrict__ out,
                             int K, int N) {
  __shared__ float tile[64][65];
  const int e = blockIdx.z;
  const int n0 = blockIdx.x * 64, k0 = blockIdx.y * 64;
  const int tid = threadIdx.x;
  const float* src = in + (size_t)e * K * N;
#pragma unroll
  for (int r = 0; r < 16; ++r) {
    const int kr = r * 4 + (tid >> 6);
    tile[kr][tid & 63] = src[(size_t)(k0 + kr) * N + n0 + (tid & 63)];
  }
  __syncthreads();
  u16* dst = out + (size_t)e * K * N + (size_t)(k0 >> 6) * ((size_t)N * 64);
#pragma unroll
  for (int r = 0; r < 8; ++r) {
    const int nr = r * 8 + (tid >> 5);
    const int kc = (tid & 31) * 2;
    ushort2 v;
    v.x = f2bf(tile[kc][nr]);
    v.y = f2bf(tile[kc + 1][nr]);
    *reinterpret_cast<ushort2*>(&dst[(size_t)(n0 + nr) * 64 + kc]) = v;
  }
}

// ---------------- Grouped GEMM: minimum-sync 2-phase double-buffer -----------
// LDS: A buf c @ c*16384 (u16), rows [256][64]; B buf c @ 32768 + c*16384.
// Swizzle: stored slot = logical ^ (row&7) (pre-swizzled global source;
// swizzled ds_read address). Staging: 8 async_load16 per thread per k-tile.
template <int KT, int NT, int NSPLIT, int PHASE>
__global__ __launch_bounds__(512, 2)
void gemm_kernel(const u16* __restrict__ Abase, const u16* __restrict__ Bt,
                 const float* __restrict__ bias, const int* __restrict__ counts,
                 const int* __restrict__ lists, const float* __restrict__ gate_p,
                 const int* __restrict__ tab,
                 u16* __restrict__ hout, float* __restrict__ yout) {
  const int e = tab[blockIdx.x * 2];
  if (e < 0) return;
  const int m0 = tab[blockIdx.x * 2 + 1];
  const int cnt = counts[e];
  const int n0 = blockIdx.y * 256;
  const int z = blockIdx.z;
  const int kb64 = z * ((KT / NSPLIT) / 64);
  constexpr int nkt = (KT / NSPLIT) / 64;
  constexpr size_t AKT = (PHASE == 1) ? (size_t)T_TOK * 64 : (size_t)T_TOK * 2 * 64;
  constexpr size_t BKT = (size_t)NT * 64;
  constexpr size_t HSLAB = (size_t)T_TOK * 2 * 64;

  const int tid = threadIdx.x;
  const int lane = tid & 63, w = tid >> 6;
  const int wm = w >> 2, wn = w & 3;
  const int l15 = lane & 15, lks = lane >> 4;

  __shared__ alignas(16) u16 lds[65536];      // 128 KB
  __shared__ int rowp[256];

  if (tid < 256) {
    const int idx = m0 + tid;
    rowp[tid] = lists[e * T_TOK + (idx < cnt ? idx : cnt - 1)];
  }
  __syncthreads();

  const int sslot = (tid & 7) ^ ((tid >> 3) & 7);
  const u16* aP[4];
  const u16* bP[4];
#pragma unroll
  for (int i = 0; i < 4; ++i) {
    const int r = i * 64 + (tid >> 3);
    const int p = rowp[r];
    const int arow = (PHASE == 1) ? (p >> 1) : p;
    aP[i] = Abase + (size_t)kb64 * AKT + (size_t)arow * 64 + sslot * 8;
    bP[i] = Bt + (size_t)e * NT * KT + (size_t)kb64 * BKT +
            (size_t)(n0 + r) * 64 + sslot * 8;
  }

  int aoff[2];
#pragma unroll
  for (int k = 0; k < 2; ++k)
    aoff[k] = l15 * 64 + (((k * 4 + lks) ^ (l15 & 7)) * 8);

  f32x4 acc[8][4];
#pragma unroll
  for (int a = 0; a < 8; ++a)
#pragma unroll
    for (int b = 0; b < 4; ++b) acc[a][b] = f32x4{0.f, 0.f, 0.f, 0.f};

  bf16x8 af[4][2], bfr[4][2];

  // stage whole k-tile TT into buf C (8 instrs/thread)
#define SGALL(C, TT)                                                           \
  _Pragma("unroll") for (int i_ = 0; i_ < 4; ++i_)                             \
    async_load16(aP[i_] + (size_t)(TT) * AKT,                                  \
                 &lds[(C) * 16384 + (i_ * 64 + w * 8) * 64]);                  \
  _Pragma("unroll") for (int i_ = 0; i_ < 4; ++i_)                             \
    async_load16(bP[i_] + (size_t)(TT) * BKT,                                  \
                 &lds[32768 + (C) * 16384 + (i_ * 64 + w * 8) * 64]);

#define RDA(C, FMH)                                                            \
  _Pragma("unroll") for (int f_ = 0; f_ < 4; ++f_)                             \
  _Pragma("unroll") for (int k_ = 0; k_ < 2; ++k_)                             \
    af[f_][k_] = *reinterpret_cast<const bf16x8*>(                             \
        &lds[(C) * 16384 + (wm * 128 + (FMH) * 64 + f_ * 16) * 64 + aoff[k_]]);

#define RDB(C)                                                                 \
  _Pragma("unroll") for (int g_ = 0; g_ < 4; ++g_)                             \
  _Pragma("unroll") for (int k_ = 0; k_ < 2; ++k_)                             \
    bfr[g_][k_] = *reinterpret_cast<const bf16x8*>(                            \
        &lds[32768 + (C) * 16384 + (wn * 64 + g_ * 16) * 64 + aoff[k_]]);

#define MMH(FMH)                                                               \
  __builtin_amdgcn_s_setprio(1);                                               \
  _Pragma("unroll") for (int f_ = 0; f_ < 4; ++f_)                             \
  _Pragma("unroll") for (int g_ = 0; g_ < 4; ++g_)                             \
  _Pragma("unroll") for (int k_ = 0; k_ < 2; ++k_)                             \
    acc[(FMH) * 4 + f_][g_] = __builtin_amdgcn_mfma_f32_16x16x32_bf16(         \
        af[f_][k_], bfr[g_][k_], acc[(FMH) * 4 + f_][g_], 0, 0, 0);            \
  __builtin_amdgcn_s_setprio(0);

  // one k-tile: stage next FIRST, then 2 {reads, lgkm, MFMA} clusters,
  // then single vmcnt(0)+barrier.
#define STEP(C, T, HASNEXT)                                                    \
  {                                                                            \
    if (HASNEXT) { SGALL((C) ^ 1, (T) + 1); }                                  \
    RDA(C, 0); RDB(C);                                                         \
    asm volatile("s_waitcnt lgkmcnt(0)" ::: "memory");                         \
    __builtin_amdgcn_sched_barrier(0);                                         \
    MMH(0);                                                                    \
    RDA(C, 1);                                                                 \
    asm volatile("s_waitcnt lgkmcnt(0)" ::: "memory");                         \
    __builtin_amdgcn_sched_barrier(0);                                         \
    MMH(1);                                                                    \
    if (HASNEXT) {                                                             \
      asm volatile("s_waitcnt vmcnt(0)" ::: "memory");                         \
      __builtin_amdgcn_sched_barrier(0);                                       \
      __builtin_amdgcn_s_barrier();                                            \
    }                                                                          \
  }

  // ---- prologue: tile 0 into buf 0 ----
  SGALL(0, 0);
  asm volatile("s_waitcnt vmcnt(0)" ::: "memory");
  __builtin_amdgcn_sched_barrier(0);
  __builtin_amdgcn_s_barrier();

#pragma unroll 1
  for (int t = 0; t < nkt; t += 2) {
    STEP(0, t, true);
    STEP(1, t + 1, (t + 2 < nkt));
  }

#undef STEP
#undef MMH
#undef RDB
#undef RDA
#undef SGALL

  // ---- epilogue ----
  const float* bias_e = bias + (size_t)e * NT;
  const float bz = (z == 0) ? 1.f : 0.f;
#pragma unroll
  for (int fm = 0; fm < 8; ++fm) {
    const int rbase = wm * 128 + (fm >> 2) * 64 + (fm & 3) * 16 + (lane >> 4) * 4;
#pragma unroll
    for (int r = 0; r < 4; ++r) {
      const int row = rbase + r;
      if (m0 + row >= cnt) continue;
      const int p = rowp[row];
#pragma unroll
      for (int nf = 0; nf < 4; ++nf) {
        const int n = n0 + wn * 64 + nf * 16 + l15;
        const float v = acc[fm][nf][r];
        if (PHASE == 1) {
          const float vb = v + bias_e[n];
          const float g = 0.5f * vb * (1.0f + erff(vb * 0.70710678118654752f));
          hout[(size_t)(n >> 6) * HSLAB + (size_t)p * 64 + (n & 63)] = f2bf(g);
        } else if (PHASE == 2) {
          yout[(size_t)z * T_TOK * 2 * NT + (size_t)p * NT + n] =
              gate_p[p] * (v + bz * bias_e[n]);
        } else {
          atomicAdd(&yout[(size_t)(p >> 1) * NT + n], gate_p[p] * (v + bz * bias_e[n]));
        }
      }
    }
  }
}

// ---------------- combine ----------------------------------------------------
__global__ void combine4_kernel(const float* __restrict__ yp, float* __restrict__ out) {
  const int i = blockIdx.x * blockDim.x + threadIdx.x;
  const int t = i >> 8, d4 = i & 255;
  const size_t r0 = (size_t)(2 * t) * 256 + d4;
  const size_t zoff = (size_t)T_TOK * 2 * DIM / 4;
  const float4 a = reinterpret_cast<const float4*>(yp)[r0];
  const float4 b = reinterpret_cast<const float4*>(yp)[r0 + 256];
  const float4 c = reinterpret_cast<const float4*>(yp)[zoff + r0];
  const float4 d = reinterpret_cast<const float4*>(yp)[zoff + r0 + 256];
  float4 o;
  o.x = a.x + b.x + c.x + d.x; o.y = a.y + b.y + c.y + d.y;
  o.z = a.z + b.z + c.z + d.z; o.w = a.w + b.w + c.w + d.w;
  reinterpret_cast<float4*>(out)[i] = o;
}

extern "C" void kernel_launch(void* const* d_in, const int* in_sizes, int n_in,
                              void* d_out, int out_size, void* d_ws, size_t ws_size,
                              hipStream_t stream) {
  const float* x  = (const float*)d_in[0];
  const float* Wr = (const float*)d_in[1];
  const float* br = (const float*)d_in[2];
  const float* gb = (const float*)d_in[3];
  const float* W1 = (const float*)d_in[4];
  const float* b1 = (const float*)d_in[5];
  const float* W2 = (const float*)d_in[6];
  const float* b2 = (const float*)d_in[7];
  float* out = (float*)d_out;

  char* ws = (char*)d_ws;
  size_t off = 0;
  int*   counts = (int*)(ws + off);   off += 256;
  int*   ttab   = (int*)(ws + off);   off += 512;
  int*   lists  = (int*)(ws + off);   off += (size_t)NE * T_TOK * 4;
  float* gate_p = (float*)(ws + off); off += (size_t)T_TOK * 2 * 4;
  u16*   xb     = (u16*)(ws + off);   off += (size_t)T_TOK * DIM * 2;
  u16*   wbuf   = (u16*)(ws + off);   off += (size_t)NE * DIM * HID * 2;
  u16*   hbuf   = (u16*)(ws + off);   off += (size_t)T_TOK * 2 * HID * 2;
  float* ypair  = (float*)(ws + off);
  const size_t need_full = off + (size_t)2 * T_TOK * 2 * DIM * 4;
  const bool use_ypair = (ws_size >= need_full);

  hipMemsetAsync(counts, 0, 32, stream);
  router_kernel<<<T_TOK / 4, 256, 0, stream>>>(x, Wr, br, gb, counts, lists, gate_p);
  tile_table_kernel<<<1, 64, 0, stream>>>(counts, ttab);
  cvt_x_kernel<<<T_TOK * DIM / 8 / 256, 256, 0, stream>>>(x, xb);
  cvt_w_kernel<<<dim3(HID / 64, DIM / 64, NE), 256, 0, stream>>>(W1, wbuf, DIM, HID);
  gemm_kernel<DIM, HID, 1, 1><<<dim3(MT_MAX, HID / 256, 1), 512, 0, stream>>>(
      xb, wbuf, b1, counts, lists, gate_p, ttab, hbuf, nullptr);
  cvt_w_kernel<<<dim3(DIM / 64, HID / 64, NE), 256, 0, stream>>>(W2, wbuf, HID, DIM);
  if (use_ypair) {
    gemm_kernel<HID, DIM, 2, 2><<<dim3(MT_MAX, DIM / 256, 2), 512, 0, stream>>>(
        hbuf, wbuf, b2, counts, lists, gate_p, ttab, nullptr, ypair);
    combine4_kernel<<<T_TOK * DIM / 4 / 256, 256, 0, stream>>>(ypair, out);
  } else {
    hipMemsetAsync(out, 0, (size_t)out_size * 4, stream);
    gemm_kernel<HID, DIM, 2, 3><<<dim3(MT_MAX, DIM / 256, 2), 512, 0, stream>>>(
        hbuf, wbuf, b2, counts, lists, gate_p, ttab, nullptr, out);
  }
}